// Round 8
// baseline (319.255 us; speedup 1.0000x reference)
//
#include <hip/hip_runtime.h>

// B=1, S=4096, D=1024, H=16, HD=64. I/O dtype detected at runtime (fp32 vs bf16).
#define SEQ 4096
#define DM  1024
#define NH  16
#define HDIM 64

typedef unsigned short u16;
typedef unsigned int   u32;
typedef __bf16 bf16x8 __attribute__((ext_vector_type(8)));
typedef float f32x4 __attribute__((ext_vector_type(4)));

__device__ __forceinline__ float bf2f(u16 u) {
    unsigned v = ((unsigned)u) << 16;
    float f;
    __builtin_memcpy(&f, &v, 4);
    return f;
}
__device__ __forceinline__ u16 f2bf(float f) {
    unsigned u;
    __builtin_memcpy(&u, &f, 4);
    return (u16)((u + 0x7fffu + ((u >> 16) & 1u)) >> 16);  // RNE
}
__device__ __forceinline__ u32 bfpack(float a, float b) {
    u32 ua, ub;
    __builtin_memcpy(&ua, &a, 4);
    __builtin_memcpy(&ub, &b, 4);
    return ((ua + 0x8000u) >> 16) | ((ub + 0x8000u) & 0xffff0000u);
}

// async global->LDS, 16B/lane. LDS dest = wave-uniform base + lane*16 (linear!).
typedef const __attribute__((address_space(1))) unsigned int gas_uint;
typedef __attribute__((address_space(3))) unsigned int las_uint;
__device__ __forceinline__ void gld16(const u16* g, u16* l) {
    __builtin_amdgcn_global_load_lds((gas_uint*)g, (las_uint*)l, 16, 0, 0);
}

__device__ __forceinline__ f32x4 mfma16(bf16x8 a, bf16x8 b, f32x4 c) {
    return __builtin_amdgcn_mfma_f32_16x16x32_bf16(a, b, c, 0, 0, 0);
}

// Q pre-scale: 1/8 (=1/sqrt(HD)) folded with log2(e) so softmax uses exp2.
#define QSCALE 0.18033688011f

// ---------------------------------------------------------------------------
// Dtype detector (bf16 weights: |v|<=~0.2; fp32 low halves decode huge).
// ---------------------------------------------------------------------------
__global__ __launch_bounds__(256) void detect_k(const u16* __restrict__ w,
                                                int* __restrict__ flags) {
    __shared__ float red[256];
    const int t = threadIdx.x;
    float mx = 0.f;
    for (int i = t; i < 4096; i += 256) {
        float v = fabsf(bf2f(w[i]));
        if (v < 3e38f) mx = fmaxf(mx, v);
    }
    red[t] = mx;
    __syncthreads();
    for (int s = 128; s > 0; s >>= 1) {
        if (t < s) red[t] = fmaxf(red[t], red[t + s]);
        __syncthreads();
    }
    if (t == 0) {
        flags[0] = (red[0] > 1e4f) ? 1 : 0;
        flags[1] = 0;
    }
}

// ---------------------------------------------------------------------------
// Fused weight prep: transpose+convert 4 weights (z) into Wt[z], biases into
// b_dst. z==0 (Wq,bq) pre-scaled by QSCALE (exp2 softmax path).
// ---------------------------------------------------------------------------
__global__ __launch_bounds__(256) void prep_w(const void* w0, const void* w1,
                                              const void* w2, const void* w3,
                                              const void* b0, const void* b1,
                                              const void* b2, const void* b3,
                                              u16* __restrict__ wt,
                                              u16* __restrict__ b_dst,
                                              const int* __restrict__ flags) {
    __shared__ u16 tile[32][33];
    const int f = flags[0];
    const int z = blockIdx.z;
    const void* win[4] = {w0, w1, w2, w3};
    const void* bin[4] = {b0, b1, b2, b3};
    const void* in = win[z];
    u16* out = wt + (size_t)z * DM * DM;
    const float scale = (z == 0) ? QSCALE : 1.0f;

    const int bx = blockIdx.x * 32;
    const int by = blockIdx.y * 32;
    const int tx = threadIdx.x & 31;
    const int ty = threadIdx.x >> 5;
#pragma unroll
    for (int i = ty; i < 32; i += 8) {
        size_t idx = (size_t)(by + i) * DM + bx + tx;
        float v = f ? ((const float*)in)[idx] : bf2f(((const u16*)in)[idx]);
        tile[i][tx] = f2bf(v * scale);
    }
    __syncthreads();
#pragma unroll
    for (int i = ty; i < 32; i += 8) out[(size_t)(bx + i) * DM + by + tx] = tile[tx][i];

    if (blockIdx.x == 0 && blockIdx.y == 0) {
        const void* bi = bin[z];
        for (int i = threadIdx.x; i < DM; i += 256) {
            float v = f ? ((const float*)bi)[i] : bf2f(((const u16*)bi)[i]);
            b_dst[z * DM + i] = f2bf(v * scale);
        }
    }
}

__global__ __launch_bounds__(256) void cvt_x8(const void* __restrict__ src,
                                              u16* __restrict__ dst,
                                              const int* __restrict__ flags) {
    const size_t i = ((size_t)blockIdx.x * 256 + threadIdx.x) * 8;
    if (flags[0]) {
        const float4* s4 = (const float4*)((const float*)src + i);
        float4 a = s4[0], b = s4[1];
        uint4 o;
        o.x = bfpack(a.x, a.y);
        o.y = bfpack(a.z, a.w);
        o.z = bfpack(b.x, b.y);
        o.w = bfpack(b.z, b.w);
        *(uint4*)(dst + i) = o;
    } else {
        *(uint4*)(dst + i) = *(const uint4*)((const u16*)src + i);
    }
}

// ---------------------------------------------------------------------------
// m97-style GEMM, B^T form, split output: C matrices are DM-wide; output
// column nb+... routes to C0/C1/C2 by nb>>10 (128-col blocks never straddle
// the 1024 boundaries). For a plain N<=1024 GEMM pass C0=C1=C2.
// ---------------------------------------------------------------------------
__global__ __launch_bounds__(256, 2) void gemm128(const u16* __restrict__ A,
                                                  const u16* __restrict__ Bt,
                                                  const u16* __restrict__ bias,
                                                  void* __restrict__ C0,
                                                  void* __restrict__ C1,
                                                  void* __restrict__ C2,
                                                  int M, int N, int K,
                                                  const int* __restrict__ flags) {
    __shared__ u16 As[128 * 32];
    __shared__ u16 Bs[128 * 32];
    const int f    = flags[0];
    const int tid  = threadIdx.x;
    const int lane = tid & 63;
    const int w    = tid >> 6;
    const int m    = lane & 15;
    const int quad = lane >> 4;
    const int wr   = w >> 1;
    const int wc   = w & 1;
    const int mb = blockIdx.x * 128;
    const int nb = blockIdx.y * 128;
    const int mat = nb >> 10;
    const int lnb = nb & 1023;
    void* C = (mat == 0) ? C0 : ((mat == 1) ? C1 : C2);

    f32x4 acc[4][4] = {};

    for (int kb = 0; kb < K; kb += 32) {
        __syncthreads();
#pragma unroll
        for (int i = 0; i < 2; ++i) {
            const int Lb = i * 256 + w * 64;
            const int L  = Lb + lane;
            const int row = L >> 2, cb = L & 3;
            gld16(&A[(size_t)(mb + row) * K + kb + cb * 8], &As[Lb * 8]);
            gld16(&Bt[(size_t)(nb + row) * K + kb + cb * 8], &Bs[Lb * 8]);
        }
        __syncthreads();

        bf16x8 af[4];
#pragma unroll
        for (int mt = 0; mt < 4; ++mt)
            af[mt] = *(const bf16x8*)&As[(wr * 64 + mt * 16 + m) * 32 + quad * 8];
#pragma unroll
        for (int ct = 0; ct < 4; ++ct) {
            bf16x8 bfr = *(const bf16x8*)&Bs[(wc * 64 + ct * 16 + m) * 32 + quad * 8];
#pragma unroll
            for (int mt = 0; mt < 4; ++mt)
                acc[mt][ct] = mfma16(af[mt], bfr, acc[mt][ct]);
        }
    }

#pragma unroll
    for (int ct = 0; ct < 4; ++ct) {
        float bv = bf2f(bias[nb + wc * 64 + ct * 16 + m]);
#pragma unroll
        for (int mt = 0; mt < 4; ++mt) {
#pragma unroll
            for (int r = 0; r < 4; ++r) {
                int row = mb + wr * 64 + mt * 16 + quad * 4 + r;
                size_t idx = (size_t)row * DM + lnb + wc * 64 + ct * 16 + m;
                float v = acc[mt][ct][r] + bv;
                if (f) ((float*)C)[idx] = v;
                else   ((u16*)C)[idx]   = f2bf(v);
            }
        }
    }
}

// ---------------------------------------------------------------------------
// Per-head V transpose: Vt[(h*64+d)*SEQ + s] = V[s*DM + h*64 + d].
// ---------------------------------------------------------------------------
__global__ __launch_bounds__(256) void vt_k(const u16* __restrict__ V,
                                            u16* __restrict__ Vt) {
    __shared__ u16 T[64][72];
    const int st = blockIdx.x;
    const int h  = blockIdx.y;
    const int t  = threadIdx.x;
    const int sl = t >> 2, c = t & 3;
    const u16* src = &V[(size_t)(st * 64 + sl) * DM + h * 64 + c * 16];
    *(uint4*)&T[sl][c * 16]     = *(const uint4*)src;
    *(uint4*)&T[sl][c * 16 + 8] = *(const uint4*)(src + 8);
    __syncthreads();
    const int dl = t >> 2, c2 = t & 3;
    u16 tmp[16];
#pragma unroll
    for (int i = 0; i < 16; ++i) tmp[i] = T[c2 * 16 + i][dl];
    u16* dst = &Vt[(size_t)(h * 64 + dl) * SEQ + st * 64 + c2 * 16];
    *(uint4*)dst       = *(const uint4*)&tmp[0];
    *(uint4*)(dst + 8) = *(const uint4*)&tmp[8];
}

// ===========================================================================
// Transposed-S flash attention, 3-way split-K, 768 blocks (3/CU, 12 waves).
// Block = 256 q-rows x 1 head x 1 K-third; 4 waves x 64 q-rows.
// S^T = K.Q^T (A=K, B=Q): C-layout row=s=quad*4+r, col=q=m IS the A-layout
// for O=P.V. Two adjacent st-tiles pack into ONE full K=32 A-frag in-lane
// (st=2p -> j=0..3, st=2p+1 -> j=4..7); matching V B-frag = two b64 reads.
// P never touches LDS; LDS = K,V double-buffered tiles (32 KB).
// Max-free softmax via exp2 (Q pre-scaled by QSCALE). XOR-16B-chunk LDS
// swizzle folded into the gld16 global fetch. Each part-task writes all 256
// q-rows of its slot (zeros where masked; part0 guarantees l>0 per row).
// ===========================================================================
__global__ __launch_bounds__(256, 3) void attn_split(const u16* __restrict__ Qb,
                                                     const u16* __restrict__ Kb,
                                                     const u16* __restrict__ Vt,
                                                     u16* __restrict__ slot0,
                                                     u16* __restrict__ slot1,
                                                     u16* __restrict__ slot2,
                                                     float* __restrict__ l0,
                                                     float* __restrict__ l1,
                                                     float* __restrict__ l2) {
    __shared__ u16 Ks[2][64 * 64];
    __shared__ u16 Vs[2][64 * 64];

    const int tid  = threadIdx.x;
    const int lane = tid & 63;
    const int w    = tid >> 6;
    const int m    = lane & 15;
    const int quad = lane >> 4;
    const int l3   = lane >> 3;
    const int cx   = ((lane & 7) ^ l3) * 8;   // staging chunk offset (u16)
    const int m7   = m & 7;

    // ---- task decode: x=XCD stream (2 heads), LPT qt2 descending ----
    const int b    = blockIdx.x;
    const int x    = b & 7;
    const int u    = b >> 3;          // 0..95
    const int qt2  = 15 - (u / 6);
    const int v6   = u % 6;
    const int head = 2 * x + (v6 / 3);
    const int part = v6 % 3;
    const int hc   = head * HDIM;
    const int n    = 4 * qt2 + 4;     // total k-tiles for this supertile
    const int k0t  = part * n / 3;
    const int k1t  = (part + 1) * n / 3 - 1;

    const int qw = qt2 * 256 + w * 64;   // this wave's q-row base
    const int dw = qw >> 6;              // wave's diagonal k-tile

    // Q B-fragments (pre-scaled by QSCALE via Wq/bq)
    bf16x8 qf[4][2];
#pragma unroll
    for (int qt4 = 0; qt4 < 4; ++qt4)
#pragma unroll
        for (int c = 0; c < 2; ++c)
            qf[qt4][c] = *(const bf16x8*)&Qb[(size_t)(qw + qt4 * 16 + m) * DM + hc + c * 32 + quad * 8];

    f32x4 o_acc[4][4] = {};
    float l_part[4] = {0.f, 0.f, 0.f, 0.f};

    // prologue: stage tile k0t -> buffer 0 (wave w stages rows w*16..+16)
#pragma unroll
    for (int i = 0; i < 2; ++i) {
        const int r = w * 16 + i * 8 + l3;
        gld16(&Kb[(size_t)(k0t * 64 + r) * DM + hc + cx], &Ks[0][(w * 16 + i * 8) * 64]);
        gld16(&Vt[(size_t)(hc + r) * SEQ + k0t * 64 + cx], &Vs[0][(w * 16 + i * 8) * 64]);
    }

    for (int kt = k0t; kt <= k1t; ++kt) {
        const int cur = (kt - k0t) & 1;
        __syncthreads();  // vmcnt(0) drain waits on DMAs issued a full iter ago

        if (kt < k1t) {
            const int nbf = 1 - cur;
            const int nkt = kt + 1;
#pragma unroll
            for (int i = 0; i < 2; ++i) {
                const int r = w * 16 + i * 8 + l3;
                gld16(&Kb[(size_t)(nkt * 64 + r) * DM + hc + cx], &Ks[nbf][(w * 16 + i * 8) * 64]);
                gld16(&Vt[(size_t)(hc + r) * SEQ + nkt * 64 + cx], &Vs[nbf][(w * 16 + i * 8) * 64]);
            }
        }

        if (kt > dw) continue;  // fully masked; barriers stay aligned

        const u16* ksb = Ks[cur];
        const u16* vsb = Vs[cur];

#pragma unroll
        for (int p = 0; p < 2; ++p) {   // st-pair: st = 2p, 2p+1
            uint4 pa_raw[4];

#pragma unroll
            for (int stt = 0; stt < 2; ++stt) {
                const int st = 2 * p + stt;
                bf16x8 kf[2];
#pragma unroll
                for (int c = 0; c < 2; ++c)
                    kf[c] = *(const bf16x8*)&ksb[(st * 16 + m) * 64 + (((c * 4 + quad) ^ m7) * 8)];

                f32x4 sc[4];
#pragma unroll
                for (int qt4 = 0; qt4 < 4; ++qt4) {
                    f32x4 a = {};
                    a = mfma16(kf[0], qf[qt4][0], a);
                    a = mfma16(kf[1], qf[qt4][1], a);
                    sc[qt4] = a;
                }

                if (kt == dw) {
#pragma unroll
                    for (int qt4 = 0; qt4 < 4; ++qt4)
#pragma unroll
                        for (int r = 0; r < 4; ++r) {
                            float pp = __builtin_amdgcn_exp2f(sc[qt4][r]);
                            sc[qt4][r] = (st * 16 + quad * 4 + r > qt4 * 16 + m) ? 0.f : pp;
                        }
                } else {
#pragma unroll
                    for (int qt4 = 0; qt4 < 4; ++qt4)
#pragma unroll
                        for (int r = 0; r < 4; ++r)
                            sc[qt4][r] = __builtin_amdgcn_exp2f(sc[qt4][r]);
                }

#pragma unroll
                for (int qt4 = 0; qt4 < 4; ++qt4) {
                    l_part[qt4] += sc[qt4][0] + sc[qt4][1] + sc[qt4][2] + sc[qt4][3];
                    const u32 pk0 = bfpack(sc[qt4][0], sc[qt4][1]);
                    const u32 pk1 = bfpack(sc[qt4][2], sc[qt4][3]);
                    if (stt == 0) { pa_raw[qt4].x = pk0; pa_raw[qt4].y = pk1; }
                    else          { pa_raw[qt4].z = pk0; pa_raw[qt4].w = pk1; }
                }
            }

            bf16x8 pa[4];
#pragma unroll
            for (int qt4 = 0; qt4 < 4; ++qt4) __builtin_memcpy(&pa[qt4], &pa_raw[qt4], 16);

            // ---- O += P.V over s in [32p, 32p+32): full K=32 MFMAs ----
#pragma unroll
            for (int dt = 0; dt < 4; ++dt) {
                const int base = (dt * 16 + m) * 64;
                const int clo = ((4 * p + (quad >> 1)) ^ m7) * 8 + (quad & 1) * 4;
                const int chi = ((4 * p + 2 + (quad >> 1)) ^ m7) * 8 + (quad & 1) * 4;
                uint2 vlo = *(const uint2*)&vsb[base + clo];
                uint2 vhi = *(const uint2*)&vsb[base + chi];
                uint4 t;
                t.x = vlo.x; t.y = vlo.y; t.z = vhi.x; t.w = vhi.y;
                bf16x8 vf;
                __builtin_memcpy(&vf, &t, 16);
#pragma unroll
                for (int qt4 = 0; qt4 < 4; ++qt4)
                    o_acc[qt4][dt] = mfma16(pa[qt4], vf, o_acc[qt4][dt]);
            }
        }
    }

    // ---- reduce l across the 4 quads (same q=m per quad-group) ----
#pragma unroll
    for (int qt4 = 0; qt4 < 4; ++qt4) {
        l_part[qt4] += __shfl_xor(l_part[qt4], 16, 64);
        l_part[qt4] += __shfl_xor(l_part[qt4], 32, 64);
    }

    // ---- store unnormalized numerator + l to this part's slot ----
    u16*   dst = (part == 0) ? slot0 : ((part == 1) ? slot1 : slot2);
    float* lb  = (part == 0) ? l0 : ((part == 1) ? l1 : l2);
#pragma unroll
    for (int qt4 = 0; qt4 < 4; ++qt4)
#pragma unroll
        for (int dt = 0; dt < 4; ++dt)
#pragma unroll
            for (int r = 0; r < 4; ++r) {
                int row = qw + qt4 * 16 + quad * 4 + r;
                dst[(size_t)row * DM + hc + dt * 16 + m] = f2bf(o_acc[qt4][dt][r]);
            }
    if (lane < 16) {
#pragma unroll
        for (int qt4 = 0; qt4 < 4; ++qt4)
            lb[head * SEQ + qw + qt4 * 16 + lane] = l_part[qt4];
    }
}

// Merge thirds in place: s0 = (s0+s1+s2) / (l0+l1+l2), all rows.
__global__ __launch_bounds__(256) void merge_k(u16* __restrict__ s0,
                                               const u16* __restrict__ s1,
                                               const u16* __restrict__ s2,
                                               const float* __restrict__ l0,
                                               const float* __restrict__ l1,
                                               const float* __restrict__ l2) {
    const int gid = blockIdx.x * 256 + threadIdx.x;  // SEQ*128 threads
    const int rl = gid >> 7;
    const int cg = gid & 127;
    const int h  = cg >> 3;
    const float inv = 1.0f / (l0[h * SEQ + rl] + l1[h * SEQ + rl] + l2[h * SEQ + rl]);
    uint4 va = *(const uint4*)(s0 + (size_t)rl * DM + cg * 8);
    uint4 vb = *(const uint4*)(s1 + (size_t)rl * DM + cg * 8);
    uint4 vc = *(const uint4*)(s2 + (size_t)rl * DM + cg * 8);
    const u16* a16 = (const u16*)&va;
    const u16* b16 = (const u16*)&vb;
    const u16* c16 = (const u16*)&vc;
    u16 oo[8];
#pragma unroll
    for (int i = 0; i < 8; ++i)
        oo[i] = f2bf((bf2f(a16[i]) + bf2f(b16[i]) + bf2f(c16[i])) * inv);
    *(uint4*)(s0 + (size_t)rl * DM + cg * 8) = *(const uint4*)&oo[0];
}

// ---------------------------------------------------------------------------
extern "C" void kernel_launch(void* const* d_in, const int* in_sizes, int n_in,
                              void* d_out, int out_size, void* d_ws, size_t ws_size,
                              hipStream_t stream) {
    (void)in_sizes; (void)n_in; (void)out_size; (void)ws_size;

    u16* ws    = (u16*)d_ws;
    int* flags = (int*)d_ws;                       // [0]=dtype, [1]=0
    u16* xc    = ws + 64;                          // SEQ*DM; Vt_g overlays after QKV GEMM
    u16* Vt_g  = xc;
    u16* Wtqkv = xc + (size_t)SEQ * DM;            // 3*DM*DM (q scaled QSCALE); -> l0/l1/l2
    u16* Wto   = Wtqkv + (size_t)3 * DM * DM;      // DM*DM
    u16* bqkv  = Wto + (size_t)DM * DM;            // 3*DM
    u16* boc   = bqkv + 3 * DM;                    // DM
    u16* Qb    = boc + DM;                         // SEQ*DM
    u16* Kb    = Qb + (size_t)SEQ * DM;            // SEQ*DM
    u16* Vb    = Kb + (size_t)SEQ * DM;            // SEQ*DM; dead after vt_k -> slot2
    u16* ab    = Vb + (size_t)SEQ * DM;            // SEQ*DM (slot0 -> merged O)
    u16* slotB = ab + (size_t)SEQ * DM;            // SEQ*DM (slot1)
    u16* slotC = Vb;                               // overlays dead V buffer
    float* l0f = (float*)Wtqkv;                    // NH*SEQ each (overlay dead Wtqkv)
    float* l1f = l0f + NH * SEQ;
    float* l2f = l1f + NH * SEQ;
    // total ~56 MB, same footprint as rounds 5-7.

    detect_k<<<1, 256, 0, stream>>>((const u16*)d_in[1], flags);

    prep_w<<<dim3(DM / 32, DM / 32, 4), 256, 0, stream>>>(
        d_in[1], d_in[3], d_in[5], d_in[7],
        d_in[2], d_in[4], d_in[6], d_in[8],
        Wtqkv, bqkv, flags);

    cvt_x8<<<SEQ * DM / 2048, 256, 0, stream>>>(d_in[0], xc, flags);

    // Fused QKV projection -> separate Q, K, V buffers (bf16)
    gemm128<<<dim3(SEQ / 128, 3 * DM / 128), 256, 0, stream>>>(
        xc, Wtqkv, bqkv, Qb, Kb, Vb, SEQ, 3 * DM, DM, flags + 1);

    // Per-head V^T (xc dead; Vt_g overlays it)
    vt_k<<<dim3(SEQ / 64, NH), 256, 0, stream>>>(Vb, Vt_g);

    attn_split<<<dim3(768), 256, 0, stream>>>(Qb, Kb, Vt_g, ab, slotB, slotC,
                                              l0f, l1f, l2f);

    merge_k<<<dim3(SEQ * 128 / 256), 256, 0, stream>>>(ab, slotB, slotC, l0f, l1f, l2f);

    gemm128<<<dim3(SEQ / 128, DM / 128), 256, 0, stream>>>(
        ab, Wto, boc, d_out, d_out, d_out, SEQ, DM, DM, flags);
}

// Round 9
// 224.680 us; speedup vs baseline: 1.4209x; 1.4209x over previous
//
#include <hip/hip_runtime.h>

// B=1, S=4096, D=1024, H=16, HD=64. I/O dtype detected at runtime (fp32 vs bf16).
#define SEQ 4096
#define DM  1024
#define NH  16
#define HDIM 64

typedef unsigned short u16;
typedef unsigned int   u32;
typedef __bf16 bf16x8 __attribute__((ext_vector_type(8)));
typedef float f32x4 __attribute__((ext_vector_type(4)));

__device__ __forceinline__ float bf2f(u16 u) {
    unsigned v = ((unsigned)u) << 16;
    float f;
    __builtin_memcpy(&f, &v, 4);
    return f;
}
__device__ __forceinline__ u16 f2bf(float f) {
    unsigned u;
    __builtin_memcpy(&u, &f, 4);
    return (u16)((u + 0x7fffu + ((u >> 16) & 1u)) >> 16);  // RNE
}
__device__ __forceinline__ u32 bfpack(float a, float b) {
    u32 ua, ub;
    __builtin_memcpy(&ua, &a, 4);
    __builtin_memcpy(&ub, &b, 4);
    return ((ua + 0x8000u) >> 16) | ((ub + 0x8000u) & 0xffff0000u);
}

// async global->LDS, 16B/lane. LDS dest = wave-uniform base + lane*16 (linear!).
typedef const __attribute__((address_space(1))) unsigned int gas_uint;
typedef __attribute__((address_space(3))) unsigned int las_uint;
__device__ __forceinline__ void gld16(const u16* g, u16* l) {
    __builtin_amdgcn_global_load_lds((gas_uint*)g, (las_uint*)l, 16, 0, 0);
}

__device__ __forceinline__ f32x4 mfma16(bf16x8 a, bf16x8 b, f32x4 c) {
    return __builtin_amdgcn_mfma_f32_16x16x32_bf16(a, b, c, 0, 0, 0);
}

// Q pre-scale: 1/8 (=1/sqrt(HD)) folded with log2(e) so softmax uses exp2.
#define QSCALE 0.18033688011f

// ---------------------------------------------------------------------------
// Dtype detector (bf16 weights: |v|<=~0.2; fp32 low halves decode huge).
// ---------------------------------------------------------------------------
__global__ __launch_bounds__(256) void detect_k(const u16* __restrict__ w,
                                                int* __restrict__ flags) {
    __shared__ float red[256];
    const int t = threadIdx.x;
    float mx = 0.f;
    for (int i = t; i < 4096; i += 256) {
        float v = fabsf(bf2f(w[i]));
        if (v < 3e38f) mx = fmaxf(mx, v);
    }
    red[t] = mx;
    __syncthreads();
    for (int s = 128; s > 0; s >>= 1) {
        if (t < s) red[t] = fmaxf(red[t], red[t + s]);
        __syncthreads();
    }
    if (t == 0) {
        flags[0] = (red[0] > 1e4f) ? 1 : 0;
        flags[1] = 0;
    }
}

// ---------------------------------------------------------------------------
// Fused weight prep: transpose+convert 4 weights (z) into Wt[z], biases into
// b_dst. z==0 (Wq,bq) pre-scaled by QSCALE (exp2 softmax path).
// ---------------------------------------------------------------------------
__global__ __launch_bounds__(256) void prep_w(const void* w0, const void* w1,
                                              const void* w2, const void* w3,
                                              const void* b0, const void* b1,
                                              const void* b2, const void* b3,
                                              u16* __restrict__ wt,
                                              u16* __restrict__ b_dst,
                                              const int* __restrict__ flags) {
    __shared__ u16 tile[32][33];
    const int f = flags[0];
    const int z = blockIdx.z;
    const void* win[4] = {w0, w1, w2, w3};
    const void* bin[4] = {b0, b1, b2, b3};
    const void* in = win[z];
    u16* out = wt + (size_t)z * DM * DM;
    const float scale = (z == 0) ? QSCALE : 1.0f;

    const int bx = blockIdx.x * 32;
    const int by = blockIdx.y * 32;
    const int tx = threadIdx.x & 31;
    const int ty = threadIdx.x >> 5;
#pragma unroll
    for (int i = ty; i < 32; i += 8) {
        size_t idx = (size_t)(by + i) * DM + bx + tx;
        float v = f ? ((const float*)in)[idx] : bf2f(((const u16*)in)[idx]);
        tile[i][tx] = f2bf(v * scale);
    }
    __syncthreads();
#pragma unroll
    for (int i = ty; i < 32; i += 8) out[(size_t)(bx + i) * DM + by + tx] = tile[tx][i];

    if (blockIdx.x == 0 && blockIdx.y == 0) {
        const void* bi = bin[z];
        for (int i = threadIdx.x; i < DM; i += 256) {
            float v = f ? ((const float*)bi)[i] : bf2f(((const u16*)bi)[i]);
            b_dst[z * DM + i] = f2bf(v * scale);
        }
    }
}

__global__ __launch_bounds__(256) void cvt_x8(const void* __restrict__ src,
                                              u16* __restrict__ dst,
                                              const int* __restrict__ flags) {
    const size_t i = ((size_t)blockIdx.x * 256 + threadIdx.x) * 8;
    if (flags[0]) {
        const float4* s4 = (const float4*)((const float*)src + i);
        float4 a = s4[0], b = s4[1];
        uint4 o;
        o.x = bfpack(a.x, a.y);
        o.y = bfpack(a.z, a.w);
        o.z = bfpack(b.x, b.y);
        o.w = bfpack(b.z, b.w);
        *(uint4*)(dst + i) = o;
    } else {
        *(uint4*)(dst + i) = *(const uint4*)((const u16*)src + i);
    }
}

// ---------------------------------------------------------------------------
// m97-style GEMM, B^T form, split output: C matrices are DM-wide; output
// column nb+... routes to C0/C1/C2 by nb>>10 (128-col blocks never straddle
// the 1024 boundaries). For a plain N<=1024 GEMM pass C0=C1=C2.
// ---------------------------------------------------------------------------
__global__ __launch_bounds__(256, 2) void gemm128(const u16* __restrict__ A,
                                                  const u16* __restrict__ Bt,
                                                  const u16* __restrict__ bias,
                                                  void* __restrict__ C0,
                                                  void* __restrict__ C1,
                                                  void* __restrict__ C2,
                                                  int M, int N, int K,
                                                  const int* __restrict__ flags) {
    __shared__ u16 As[128 * 32];
    __shared__ u16 Bs[128 * 32];
    const int f    = flags[0];
    const int tid  = threadIdx.x;
    const int lane = tid & 63;
    const int w    = tid >> 6;
    const int m    = lane & 15;
    const int quad = lane >> 4;
    const int wr   = w >> 1;
    const int wc   = w & 1;
    const int mb = blockIdx.x * 128;
    const int nb = blockIdx.y * 128;
    const int mat = nb >> 10;
    const int lnb = nb & 1023;
    void* C = (mat == 0) ? C0 : ((mat == 1) ? C1 : C2);

    f32x4 acc[4][4] = {};

    for (int kb = 0; kb < K; kb += 32) {
        __syncthreads();
#pragma unroll
        for (int i = 0; i < 2; ++i) {
            const int Lb = i * 256 + w * 64;
            const int L  = Lb + lane;
            const int row = L >> 2, cb = L & 3;
            gld16(&A[(size_t)(mb + row) * K + kb + cb * 8], &As[Lb * 8]);
            gld16(&Bt[(size_t)(nb + row) * K + kb + cb * 8], &Bs[Lb * 8]);
        }
        __syncthreads();

        bf16x8 af[4];
#pragma unroll
        for (int mt = 0; mt < 4; ++mt)
            af[mt] = *(const bf16x8*)&As[(wr * 64 + mt * 16 + m) * 32 + quad * 8];
#pragma unroll
        for (int ct = 0; ct < 4; ++ct) {
            bf16x8 bfr = *(const bf16x8*)&Bs[(wc * 64 + ct * 16 + m) * 32 + quad * 8];
#pragma unroll
            for (int mt = 0; mt < 4; ++mt)
                acc[mt][ct] = mfma16(af[mt], bfr, acc[mt][ct]);
        }
    }

#pragma unroll
    for (int ct = 0; ct < 4; ++ct) {
        float bv = bf2f(bias[nb + wc * 64 + ct * 16 + m]);
#pragma unroll
        for (int mt = 0; mt < 4; ++mt) {
#pragma unroll
            for (int r = 0; r < 4; ++r) {
                int row = mb + wr * 64 + mt * 16 + quad * 4 + r;
                size_t idx = (size_t)row * DM + lnb + wc * 64 + ct * 16 + m;
                float v = acc[mt][ct][r] + bv;
                if (f) ((float*)C)[idx] = v;
                else   ((u16*)C)[idx]   = f2bf(v);
            }
        }
    }
}

// ---------------------------------------------------------------------------
// Per-head V transpose: Vt[(h*64+d)*SEQ + s] = V[s*DM + h*64 + d].
// ---------------------------------------------------------------------------
__global__ __launch_bounds__(256) void vt_k(const u16* __restrict__ V,
                                            u16* __restrict__ Vt) {
    __shared__ u16 T[64][72];
    const int st = blockIdx.x;
    const int h  = blockIdx.y;
    const int t  = threadIdx.x;
    const int sl = t >> 2, c = t & 3;
    const u16* src = &V[(size_t)(st * 64 + sl) * DM + h * 64 + c * 16];
    *(uint4*)&T[sl][c * 16]     = *(const uint4*)src;
    *(uint4*)&T[sl][c * 16 + 8] = *(const uint4*)(src + 8);
    __syncthreads();
    const int dl = t >> 2, c2 = t & 3;
    u16 tmp[16];
#pragma unroll
    for (int i = 0; i < 16; ++i) tmp[i] = T[c2 * 16 + i][dl];
    u16* dst = &Vt[(size_t)(h * 64 + dl) * SEQ + st * 64 + c2 * 16];
    *(uint4*)dst       = *(const uint4*)&tmp[0];
    *(uint4*)(dst + 8) = *(const uint4*)&tmp[8];
}

// ===========================================================================
// Transposed-S flash attention, 3-way split-K, 768 blocks.
// Block = 256 q-rows x 1 head x 1 K-third; 4 waves x 64 q-rows.
// S^T = K.Q^T (A=K, B=Q): C-layout row=s=quad*4+r, col=q=m IS the A-layout
// for O=P.V. Two adjacent st-tiles pack into ONE full K=32 A-frag in-lane
// (st=2p -> j=0..3, st=2p+1 -> j=4..7); matching V B-frag = two b64 reads.
// P never touches LDS; LDS = K,V double-buffered tiles (32 KB).
// Max-free softmax via exp2 (Q pre-scaled by QSCALE). XOR-16B-chunk LDS
// swizzle folded into the gld16 global fetch.
// __launch_bounds__(256,2): round 8's (256,3) capped VGPR at 84 and spilled
// to scratch (FETCH 12->65MB, WRITE 17->84MB, MfmaUtil 8.8%) — the live set
// (qf 32 + o_acc 64 + sc/pa/kf/vf ~56 + addr) needs the 2-wave/EU budget.
// ===========================================================================
__global__ __launch_bounds__(256, 2) void attn_split(const u16* __restrict__ Qb,
                                                     const u16* __restrict__ Kb,
                                                     const u16* __restrict__ Vt,
                                                     u16* __restrict__ slot0,
                                                     u16* __restrict__ slot1,
                                                     u16* __restrict__ slot2,
                                                     float* __restrict__ l0,
                                                     float* __restrict__ l1,
                                                     float* __restrict__ l2) {
    __shared__ u16 Ks[2][64 * 64];
    __shared__ u16 Vs[2][64 * 64];

    const int tid  = threadIdx.x;
    const int lane = tid & 63;
    const int w    = tid >> 6;
    const int m    = lane & 15;
    const int quad = lane >> 4;
    const int l3   = lane >> 3;
    const int cx   = ((lane & 7) ^ l3) * 8;   // staging chunk offset (u16)
    const int m7   = m & 7;

    // ---- task decode: x=XCD stream (2 heads), LPT qt2 descending ----
    const int b    = blockIdx.x;
    const int x    = b & 7;
    const int u    = b >> 3;          // 0..95
    const int qt2  = 15 - (u / 6);
    const int v6   = u % 6;
    const int head = 2 * x + (v6 / 3);
    const int part = v6 % 3;
    const int hc   = head * HDIM;
    const int n    = 4 * qt2 + 4;     // total k-tiles for this supertile
    const int k0t  = part * n / 3;
    const int k1t  = (part + 1) * n / 3 - 1;

    const int qw = qt2 * 256 + w * 64;   // this wave's q-row base
    const int dw = qw >> 6;              // wave's diagonal k-tile

    // Q B-fragments (pre-scaled by QSCALE via Wq/bq)
    bf16x8 qf[4][2];
#pragma unroll
    for (int qt4 = 0; qt4 < 4; ++qt4)
#pragma unroll
        for (int c = 0; c < 2; ++c)
            qf[qt4][c] = *(const bf16x8*)&Qb[(size_t)(qw + qt4 * 16 + m) * DM + hc + c * 32 + quad * 8];

    f32x4 o_acc[4][4] = {};
    float l_part[4] = {0.f, 0.f, 0.f, 0.f};

    // prologue: stage tile k0t -> buffer 0 (wave w stages rows w*16..+16)
#pragma unroll
    for (int i = 0; i < 2; ++i) {
        const int r = w * 16 + i * 8 + l3;
        gld16(&Kb[(size_t)(k0t * 64 + r) * DM + hc + cx], &Ks[0][(w * 16 + i * 8) * 64]);
        gld16(&Vt[(size_t)(hc + r) * SEQ + k0t * 64 + cx], &Vs[0][(w * 16 + i * 8) * 64]);
    }

    for (int kt = k0t; kt <= k1t; ++kt) {
        const int cur = (kt - k0t) & 1;
        __syncthreads();  // vmcnt(0) drain waits on DMAs issued a full iter ago

        if (kt < k1t) {
            const int nbf = 1 - cur;
            const int nkt = kt + 1;
#pragma unroll
            for (int i = 0; i < 2; ++i) {
                const int r = w * 16 + i * 8 + l3;
                gld16(&Kb[(size_t)(nkt * 64 + r) * DM + hc + cx], &Ks[nbf][(w * 16 + i * 8) * 64]);
                gld16(&Vt[(size_t)(hc + r) * SEQ + nkt * 64 + cx], &Vs[nbf][(w * 16 + i * 8) * 64]);
            }
        }

        if (kt > dw) continue;  // fully masked; barriers stay aligned

        const u16* ksb = Ks[cur];
        const u16* vsb = Vs[cur];

#pragma unroll
        for (int p = 0; p < 2; ++p) {   // st-pair: st = 2p, 2p+1
            uint4 pa_raw[4];

#pragma unroll
            for (int stt = 0; stt < 2; ++stt) {
                const int st = 2 * p + stt;
                bf16x8 kf[2];
#pragma unroll
                for (int c = 0; c < 2; ++c)
                    kf[c] = *(const bf16x8*)&ksb[(st * 16 + m) * 64 + (((c * 4 + quad) ^ m7) * 8)];

                f32x4 sc[4];
#pragma unroll
                for (int qt4 = 0; qt4 < 4; ++qt4) {
                    f32x4 a = {};
                    a = mfma16(kf[0], qf[qt4][0], a);
                    a = mfma16(kf[1], qf[qt4][1], a);
                    sc[qt4] = a;
                }

                if (kt == dw) {
#pragma unroll
                    for (int qt4 = 0; qt4 < 4; ++qt4)
#pragma unroll
                        for (int r = 0; r < 4; ++r) {
                            float pp = __builtin_amdgcn_exp2f(sc[qt4][r]);
                            sc[qt4][r] = (st * 16 + quad * 4 + r > qt4 * 16 + m) ? 0.f : pp;
                        }
                } else {
#pragma unroll
                    for (int qt4 = 0; qt4 < 4; ++qt4)
#pragma unroll
                        for (int r = 0; r < 4; ++r)
                            sc[qt4][r] = __builtin_amdgcn_exp2f(sc[qt4][r]);
                }

#pragma unroll
                for (int qt4 = 0; qt4 < 4; ++qt4) {
                    l_part[qt4] += sc[qt4][0] + sc[qt4][1] + sc[qt4][2] + sc[qt4][3];
                    const u32 pk0 = bfpack(sc[qt4][0], sc[qt4][1]);
                    const u32 pk1 = bfpack(sc[qt4][2], sc[qt4][3]);
                    if (stt == 0) { pa_raw[qt4].x = pk0; pa_raw[qt4].y = pk1; }
                    else          { pa_raw[qt4].z = pk0; pa_raw[qt4].w = pk1; }
                }
            }

            bf16x8 pa[4];
#pragma unroll
            for (int qt4 = 0; qt4 < 4; ++qt4) __builtin_memcpy(&pa[qt4], &pa_raw[qt4], 16);

            // ---- O += P.V over s in [32p, 32p+32): full K=32 MFMAs ----
#pragma unroll
            for (int dt = 0; dt < 4; ++dt) {
                const int base = (dt * 16 + m) * 64;
                const int clo = ((4 * p + (quad >> 1)) ^ m7) * 8 + (quad & 1) * 4;
                const int chi = ((4 * p + 2 + (quad >> 1)) ^ m7) * 8 + (quad & 1) * 4;
                uint2 vlo = *(const uint2*)&vsb[base + clo];
                uint2 vhi = *(const uint2*)&vsb[base + chi];
                uint4 t;
                t.x = vlo.x; t.y = vlo.y; t.z = vhi.x; t.w = vhi.y;
                bf16x8 vf;
                __builtin_memcpy(&vf, &t, 16);
#pragma unroll
                for (int qt4 = 0; qt4 < 4; ++qt4)
                    o_acc[qt4][dt] = mfma16(pa[qt4], vf, o_acc[qt4][dt]);
            }
        }
    }

    // ---- reduce l across the 4 quads (same q=m per quad-group) ----
#pragma unroll
    for (int qt4 = 0; qt4 < 4; ++qt4) {
        l_part[qt4] += __shfl_xor(l_part[qt4], 16, 64);
        l_part[qt4] += __shfl_xor(l_part[qt4], 32, 64);
    }

    // ---- store unnormalized numerator + l to this part's slot ----
    u16*   dst = (part == 0) ? slot0 : ((part == 1) ? slot1 : slot2);
    float* lb  = (part == 0) ? l0 : ((part == 1) ? l1 : l2);
#pragma unroll
    for (int qt4 = 0; qt4 < 4; ++qt4)
#pragma unroll
        for (int dt = 0; dt < 4; ++dt)
#pragma unroll
            for (int r = 0; r < 4; ++r) {
                int row = qw + qt4 * 16 + quad * 4 + r;
                dst[(size_t)row * DM + hc + dt * 16 + m] = f2bf(o_acc[qt4][dt][r]);
            }
    if (lane < 16) {
#pragma unroll
        for (int qt4 = 0; qt4 < 4; ++qt4)
            lb[head * SEQ + qw + qt4 * 16 + lane] = l_part[qt4];
    }
}

// Merge thirds in place: s0 = (s0+s1+s2) / (l0+l1+l2), all rows.
__global__ __launch_bounds__(256) void merge_k(u16* __restrict__ s0,
                                               const u16* __restrict__ s1,
                                               const u16* __restrict__ s2,
                                               const float* __restrict__ l0,
                                               const float* __restrict__ l1,
                                               const float* __restrict__ l2) {
    const int gid = blockIdx.x * 256 + threadIdx.x;  // SEQ*128 threads
    const int rl = gid >> 7;
    const int cg = gid & 127;
    const int h  = cg >> 3;
    const float inv = 1.0f / (l0[h * SEQ + rl] + l1[h * SEQ + rl] + l2[h * SEQ + rl]);
    uint4 va = *(const uint4*)(s0 + (size_t)rl * DM + cg * 8);
    uint4 vb = *(const uint4*)(s1 + (size_t)rl * DM + cg * 8);
    uint4 vc = *(const uint4*)(s2 + (size_t)rl * DM + cg * 8);
    const u16* a16 = (const u16*)&va;
    const u16* b16 = (const u16*)&vb;
    const u16* c16 = (const u16*)&vc;
    u16 oo[8];
#pragma unroll
    for (int i = 0; i < 8; ++i)
        oo[i] = f2bf((bf2f(a16[i]) + bf2f(b16[i]) + bf2f(c16[i])) * inv);
    *(uint4*)(s0 + (size_t)rl * DM + cg * 8) = *(const uint4*)&oo[0];
}

// ---------------------------------------------------------------------------
extern "C" void kernel_launch(void* const* d_in, const int* in_sizes, int n_in,
                              void* d_out, int out_size, void* d_ws, size_t ws_size,
                              hipStream_t stream) {
    (void)in_sizes; (void)n_in; (void)out_size; (void)ws_size;

    u16* ws    = (u16*)d_ws;
    int* flags = (int*)d_ws;                       // [0]=dtype, [1]=0
    u16* xc    = ws + 64;                          // SEQ*DM; Vt_g overlays after QKV GEMM
    u16* Vt_g  = xc;
    u16* Wtqkv = xc + (size_t)SEQ * DM;            // 3*DM*DM (q scaled QSCALE); -> l0/l1/l2
    u16* Wto   = Wtqkv + (size_t)3 * DM * DM;      // DM*DM
    u16* bqkv  = Wto + (size_t)DM * DM;            // 3*DM
    u16* boc   = bqkv + 3 * DM;                    // DM
    u16* Qb    = boc + DM;                         // SEQ*DM
    u16* Kb    = Qb + (size_t)SEQ * DM;            // SEQ*DM
    u16* Vb    = Kb + (size_t)SEQ * DM;            // SEQ*DM; dead after vt_k -> slot2
    u16* ab    = Vb + (size_t)SEQ * DM;            // SEQ*DM (slot0 -> merged O)
    u16* slotB = ab + (size_t)SEQ * DM;            // SEQ*DM (slot1)
    u16* slotC = Vb;                               // overlays dead V buffer
    float* l0f = (float*)Wtqkv;                    // NH*SEQ each (overlay dead Wtqkv)
    float* l1f = l0f + NH * SEQ;
    float* l2f = l1f + NH * SEQ;
    // total ~56 MB, same footprint as rounds 5-8.

    detect_k<<<1, 256, 0, stream>>>((const u16*)d_in[1], flags);

    prep_w<<<dim3(DM / 32, DM / 32, 4), 256, 0, stream>>>(
        d_in[1], d_in[3], d_in[5], d_in[7],
        d_in[2], d_in[4], d_in[6], d_in[8],
        Wtqkv, bqkv, flags);

    cvt_x8<<<SEQ * DM / 2048, 256, 0, stream>>>(d_in[0], xc, flags);

    // Fused QKV projection -> separate Q, K, V buffers (bf16)
    gemm128<<<dim3(SEQ / 128, 3 * DM / 128), 256, 0, stream>>>(
        xc, Wtqkv, bqkv, Qb, Kb, Vb, SEQ, 3 * DM, DM, flags + 1);

    // Per-head V^T (xc dead; Vt_g overlays it)
    vt_k<<<dim3(SEQ / 64, NH), 256, 0, stream>>>(Vb, Vt_g);

    attn_split<<<dim3(768), 256, 0, stream>>>(Qb, Kb, Vt_g, ab, slotB, slotC,
                                              l0f, l1f, l2f);

    merge_k<<<dim3(SEQ * 128 / 256), 256, 0, stream>>>(ab, slotB, slotC, l0f, l1f, l2f);

    gemm128<<<dim3(SEQ / 128, DM / 128), 256, 0, stream>>>(
        ab, Wto, boc, d_out, d_out, d_out, SEQ, DM, DM, flags);
}

// Round 10
// 220.464 us; speedup vs baseline: 1.4481x; 1.0191x over previous
//
#include <hip/hip_runtime.h>

// B=1, S=4096, D=1024, H=16, HD=64. I/O dtype detected at runtime (fp32 vs bf16).
#define SEQ 4096
#define DM  1024
#define NH  16
#define HDIM 64

typedef unsigned short u16;
typedef unsigned int   u32;
typedef __bf16 bf16x8 __attribute__((ext_vector_type(8)));
typedef float f32x4 __attribute__((ext_vector_type(4)));

__device__ __forceinline__ float bf2f(u16 u) {
    unsigned v = ((unsigned)u) << 16;
    float f;
    __builtin_memcpy(&f, &v, 4);
    return f;
}
__device__ __forceinline__ u16 f2bf(float f) {
    unsigned u;
    __builtin_memcpy(&u, &f, 4);
    return (u16)((u + 0x7fffu + ((u >> 16) & 1u)) >> 16);  // RNE
}
__device__ __forceinline__ u32 bfpack(float a, float b) {
    u32 ua, ub;
    __builtin_memcpy(&ua, &a, 4);
    __builtin_memcpy(&ub, &b, 4);
    return ((ua + 0x8000u) >> 16) | ((ub + 0x8000u) & 0xffff0000u);
}

// async global->LDS, 16B/lane. LDS dest = wave-uniform base + lane*16 (linear!).
typedef const __attribute__((address_space(1))) unsigned int gas_uint;
typedef __attribute__((address_space(3))) unsigned int las_uint;
__device__ __forceinline__ void gld16(const u16* g, u16* l) {
    __builtin_amdgcn_global_load_lds((gas_uint*)g, (las_uint*)l, 16, 0, 0);
}

__device__ __forceinline__ f32x4 mfma16(bf16x8 a, bf16x8 b, f32x4 c) {
    return __builtin_amdgcn_mfma_f32_16x16x32_bf16(a, b, c, 0, 0, 0);
}

// Q pre-scale: 1/8 (=1/sqrt(HD)) folded with log2(e) so softmax uses exp2.
#define QSCALE 0.18033688011f

// ---------------------------------------------------------------------------
// Dtype detector (bf16 weights: |v|<=~0.2; fp32 low halves decode huge).
// ---------------------------------------------------------------------------
__global__ __launch_bounds__(256) void detect_k(const u16* __restrict__ w,
                                                int* __restrict__ flags) {
    __shared__ float red[256];
    const int t = threadIdx.x;
    float mx = 0.f;
    for (int i = t; i < 4096; i += 256) {
        float v = fabsf(bf2f(w[i]));
        if (v < 3e38f) mx = fmaxf(mx, v);
    }
    red[t] = mx;
    __syncthreads();
    for (int s = 128; s > 0; s >>= 1) {
        if (t < s) red[t] = fmaxf(red[t], red[t + s]);
        __syncthreads();
    }
    if (t == 0) {
        flags[0] = (red[0] > 1e4f) ? 1 : 0;
        flags[1] = 0;
    }
}

// ---------------------------------------------------------------------------
// Fused weight prep: transpose+convert 4 weights (z) into Wt[z], biases into
// b_dst. z==0 (Wq,bq) pre-scaled by QSCALE (exp2 softmax path).
// ---------------------------------------------------------------------------
__global__ __launch_bounds__(256) void prep_w(const void* w0, const void* w1,
                                              const void* w2, const void* w3,
                                              const void* b0, const void* b1,
                                              const void* b2, const void* b3,
                                              u16* __restrict__ wt,
                                              u16* __restrict__ b_dst,
                                              const int* __restrict__ flags) {
    __shared__ u16 tile[32][33];
    const int f = flags[0];
    const int z = blockIdx.z;
    const void* win[4] = {w0, w1, w2, w3};
    const void* bin[4] = {b0, b1, b2, b3};
    const void* in = win[z];
    u16* out = wt + (size_t)z * DM * DM;
    const float scale = (z == 0) ? QSCALE : 1.0f;

    const int bx = blockIdx.x * 32;
    const int by = blockIdx.y * 32;
    const int tx = threadIdx.x & 31;
    const int ty = threadIdx.x >> 5;
#pragma unroll
    for (int i = ty; i < 32; i += 8) {
        size_t idx = (size_t)(by + i) * DM + bx + tx;
        float v = f ? ((const float*)in)[idx] : bf2f(((const u16*)in)[idx]);
        tile[i][tx] = f2bf(v * scale);
    }
    __syncthreads();
#pragma unroll
    for (int i = ty; i < 32; i += 8) out[(size_t)(bx + i) * DM + by + tx] = tile[tx][i];

    if (blockIdx.x == 0 && blockIdx.y == 0) {
        const void* bi = bin[z];
        for (int i = threadIdx.x; i < DM; i += 256) {
            float v = f ? ((const float*)bi)[i] : bf2f(((const u16*)bi)[i]);
            b_dst[z * DM + i] = f2bf(v * scale);
        }
    }
}

__global__ __launch_bounds__(256) void cvt_x8(const void* __restrict__ src,
                                              u16* __restrict__ dst,
                                              const int* __restrict__ flags) {
    const size_t i = ((size_t)blockIdx.x * 256 + threadIdx.x) * 8;
    if (flags[0]) {
        const float4* s4 = (const float4*)((const float*)src + i);
        float4 a = s4[0], b = s4[1];
        uint4 o;
        o.x = bfpack(a.x, a.y);
        o.y = bfpack(a.z, a.w);
        o.z = bfpack(b.x, b.y);
        o.w = bfpack(b.z, b.w);
        *(uint4*)(dst + i) = o;
    } else {
        *(uint4*)(dst + i) = *(const uint4*)((const u16*)src + i);
    }
}

// ---------------------------------------------------------------------------
// m97-style GEMM, B^T form, split output (QKV projection). 128x128 tile.
// ---------------------------------------------------------------------------
__global__ __launch_bounds__(256, 2) void gemm128(const u16* __restrict__ A,
                                                  const u16* __restrict__ Bt,
                                                  const u16* __restrict__ bias,
                                                  void* __restrict__ C0,
                                                  void* __restrict__ C1,
                                                  void* __restrict__ C2,
                                                  int M, int N, int K,
                                                  const int* __restrict__ flags) {
    __shared__ u16 As[128 * 32];
    __shared__ u16 Bs[128 * 32];
    const int f    = flags[0];
    const int tid  = threadIdx.x;
    const int lane = tid & 63;
    const int w    = tid >> 6;
    const int m    = lane & 15;
    const int quad = lane >> 4;
    const int wr   = w >> 1;
    const int wc   = w & 1;
    const int mb = blockIdx.x * 128;
    const int nb = blockIdx.y * 128;
    const int mat = nb >> 10;
    const int lnb = nb & 1023;
    void* C = (mat == 0) ? C0 : ((mat == 1) ? C1 : C2);

    f32x4 acc[4][4] = {};

    for (int kb = 0; kb < K; kb += 32) {
        __syncthreads();
#pragma unroll
        for (int i = 0; i < 2; ++i) {
            const int Lb = i * 256 + w * 64;
            const int L  = Lb + lane;
            const int row = L >> 2, cb = L & 3;
            gld16(&A[(size_t)(mb + row) * K + kb + cb * 8], &As[Lb * 8]);
            gld16(&Bt[(size_t)(nb + row) * K + kb + cb * 8], &Bs[Lb * 8]);
        }
        __syncthreads();

        bf16x8 af[4];
#pragma unroll
        for (int mt = 0; mt < 4; ++mt)
            af[mt] = *(const bf16x8*)&As[(wr * 64 + mt * 16 + m) * 32 + quad * 8];
#pragma unroll
        for (int ct = 0; ct < 4; ++ct) {
            bf16x8 bfr = *(const bf16x8*)&Bs[(wc * 64 + ct * 16 + m) * 32 + quad * 8];
#pragma unroll
            for (int mt = 0; mt < 4; ++mt)
                acc[mt][ct] = mfma16(af[mt], bfr, acc[mt][ct]);
        }
    }

#pragma unroll
    for (int ct = 0; ct < 4; ++ct) {
        float bv = bf2f(bias[nb + wc * 64 + ct * 16 + m]);
#pragma unroll
        for (int mt = 0; mt < 4; ++mt) {
#pragma unroll
            for (int r = 0; r < 4; ++r) {
                int row = mb + wr * 64 + mt * 16 + quad * 4 + r;
                size_t idx = (size_t)row * DM + lnb + wc * 64 + ct * 16 + m;
                float v = acc[mt][ct][r] + bv;
                if (f) ((float*)C)[idx] = v;
                else   ((u16*)C)[idx]   = f2bf(v);
            }
        }
    }
}

// ---------------------------------------------------------------------------
// 128x64-tile GEMM (out-projection): grid (M/128, N/64) = 512 blocks -> 2/CU.
// Wave w: rows w*32..+32 (2 m-frags) x 64 cols (4 frags). acc = 32 AGPR.
// ---------------------------------------------------------------------------
__global__ __launch_bounds__(256, 2) void gemm_n64(const u16* __restrict__ A,
                                                   const u16* __restrict__ Bt,
                                                   const u16* __restrict__ bias,
                                                   void* __restrict__ C,
                                                   int M, int N, int K,
                                                   const int* __restrict__ flags) {
    __shared__ u16 As[128 * 32];
    __shared__ u16 Bs[64 * 32];
    const int f    = flags[0];
    const int tid  = threadIdx.x;
    const int lane = tid & 63;
    const int w    = tid >> 6;
    const int m    = lane & 15;
    const int quad = lane >> 4;
    const int mb = blockIdx.x * 128;
    const int nb = blockIdx.y * 64;

    f32x4 acc[2][4] = {};

    for (int kb = 0; kb < K; kb += 32) {
        __syncthreads();
#pragma unroll
        for (int i = 0; i < 2; ++i) {      // A: 8 chunks, wave w does 2w, 2w+1
            const int Lb = (2 * w + i) * 64;
            const int L  = Lb + lane;
            const int row = L >> 2, cb = L & 3;
            gld16(&A[(size_t)(mb + row) * K + kb + cb * 8], &As[Lb * 8]);
        }
        {                                   // B: wave w stages rows w*16..+16
            const int L = w * 64 + lane;
            const int row = L >> 2, cb = L & 3;
            gld16(&Bt[(size_t)(nb + row) * K + kb + cb * 8], &Bs[w * 512]);
        }
        __syncthreads();

        bf16x8 af[2];
#pragma unroll
        for (int mt = 0; mt < 2; ++mt)
            af[mt] = *(const bf16x8*)&As[(w * 32 + mt * 16 + m) * 32 + quad * 8];
#pragma unroll
        for (int ct = 0; ct < 4; ++ct) {
            bf16x8 bfr = *(const bf16x8*)&Bs[(ct * 16 + m) * 32 + quad * 8];
#pragma unroll
            for (int mt = 0; mt < 2; ++mt)
                acc[mt][ct] = mfma16(af[mt], bfr, acc[mt][ct]);
        }
    }

#pragma unroll
    for (int ct = 0; ct < 4; ++ct) {
        float bv = bf2f(bias[nb + ct * 16 + m]);
#pragma unroll
        for (int mt = 0; mt < 2; ++mt) {
#pragma unroll
            for (int r = 0; r < 4; ++r) {
                int row = mb + w * 32 + mt * 16 + quad * 4 + r;
                size_t idx = (size_t)row * N + nb + ct * 16 + m;
                float v = acc[mt][ct][r] + bv;
                if (f) ((float*)C)[idx] = v;
                else   ((u16*)C)[idx]   = f2bf(v);
            }
        }
    }
}

// ---------------------------------------------------------------------------
// Per-head V transpose: Vt[(h*64+d)*SEQ + s] = V[s*DM + h*64 + d].
// ---------------------------------------------------------------------------
__global__ __launch_bounds__(256) void vt_k(const u16* __restrict__ V,
                                            u16* __restrict__ Vt) {
    __shared__ u16 T[64][72];
    const int st = blockIdx.x;
    const int h  = blockIdx.y;
    const int t  = threadIdx.x;
    const int sl = t >> 2, c = t & 3;
    const u16* src = &V[(size_t)(st * 64 + sl) * DM + h * 64 + c * 16];
    *(uint4*)&T[sl][c * 16]     = *(const uint4*)src;
    *(uint4*)&T[sl][c * 16 + 8] = *(const uint4*)(src + 8);
    __syncthreads();
    const int dl = t >> 2, c2 = t & 3;
    u16 tmp[16];
#pragma unroll
    for (int i = 0; i < 16; ++i) tmp[i] = T[c2 * 16 + i][dl];
    u16* dst = &Vt[(size_t)(h * 64 + dl) * SEQ + st * 64 + c2 * 16];
    *(uint4*)dst       = *(const uint4*)&tmp[0];
    *(uint4*)(dst + 8) = *(const uint4*)&tmp[8];
}

// ===========================================================================
// Transposed-S flash attention, 3-way split-K, BK=128 (two 64-k-tiles per
// barrier -> half the barriers/loop overhead of round 9). 768 blocks.
// Block = 256 q-rows x 1 head x 1 K-third; 4 waves x 64 q-rows.
// S^T = K.Q^T (A=K, B=Q); st-paired register-only P -> full K=32 PV MFMAs.
// LDS: Ks[2][128x64] + Vs[2][64x128] = 64 KB -> 2 blocks/CU.
// (256,2): (256,3) spilled in round 8 (VGPR capped 84 < live set).
// ===========================================================================
__global__ __launch_bounds__(256, 2) void attn_split(const u16* __restrict__ Qb,
                                                     const u16* __restrict__ Kb,
                                                     const u16* __restrict__ Vt,
                                                     u16* __restrict__ slot0,
                                                     u16* __restrict__ slot1,
                                                     u16* __restrict__ slot2,
                                                     float* __restrict__ l0,
                                                     float* __restrict__ l1,
                                                     float* __restrict__ l2) {
    __shared__ u16 Ks[2][128 * 64];
    __shared__ u16 Vs[2][64 * 128];

    const int tid  = threadIdx.x;
    const int lane = tid & 63;
    const int w    = tid >> 6;
    const int m    = lane & 15;
    const int quad = lane >> 4;
    const int l3   = lane >> 3;               // 0..7
    const int l4   = lane >> 4;               // 0..3
    const int m7   = m & 7;
    const int cxk  = ((lane & 7) ^ l3) * 8;   // K staging chunk (row%8 = l3)

    // ---- task decode: x=XCD stream (2 heads), LPT qt2 descending ----
    const int b    = blockIdx.x;
    const int x    = b & 7;
    const int u    = b >> 3;          // 0..95
    const int qt2  = 15 - (u / 6);
    const int v6   = u % 6;
    const int head = 2 * x + (v6 / 3);
    const int part = v6 % 3;
    const int hc   = head * HDIM;
    const int n128 = 2 * qt2 + 2;     // total 128-k-tiles for this supertile
    const int k0t  = part * n128 / 3;
    const int k1t  = (part + 1) * n128 / 3 - 1;   // may be < k0t (empty part)

    const int qw = qt2 * 256 + w * 64;   // this wave's q-row base
    const int dw = qw >> 6;              // wave's diagonal 64-tile index

    // Q B-fragments (pre-scaled by QSCALE via Wq/bq)
    bf16x8 qf[4][2];
#pragma unroll
    for (int qt4 = 0; qt4 < 4; ++qt4)
#pragma unroll
        for (int c = 0; c < 2; ++c)
            qf[qt4][c] = *(const bf16x8*)&Qb[(size_t)(qw + qt4 * 16 + m) * DM + hc + c * 32 + quad * 8];

    f32x4 o_acc[4][4] = {};
    float l_part[4] = {0.f, 0.f, 0.f, 0.f};

    // prologue: stage tile k0t -> buffer 0
    // K: 128 s-rows x 64 hd (row=128B); wave w rows w*32..+32, 8 rows/instr.
    // V: 64 d-rows x 128 s (row=256B); wave w rows w*16..+16, 4 rows/instr.
#pragma unroll
    for (int i = 0; i < 4; ++i) {
        const int kr = w * 32 + i * 8 + l3;
        gld16(&Kb[(size_t)(k0t * 128 + kr) * DM + hc + cxk], &Ks[0][(w * 32 + i * 8) * 64]);
        const int vr = w * 16 + i * 4 + l4;
        const int cxv = ((lane & 15) ^ ((i * 4 + l4) & 7)) * 8;
        gld16(&Vt[(size_t)(hc + vr) * SEQ + k0t * 128 + cxv], &Vs[0][(w * 16 + i * 4) * 128]);
    }

    for (int kt = k0t; kt <= k1t; ++kt) {
        const int cur = (kt - k0t) & 1;
        __syncthreads();  // vmcnt(0) drain waits on DMAs issued a full iter ago

        if (kt < k1t) {
            const int nbf = 1 - cur;
            const int nkt = kt + 1;
#pragma unroll
            for (int i = 0; i < 4; ++i) {
                const int kr = w * 32 + i * 8 + l3;
                gld16(&Kb[(size_t)(nkt * 128 + kr) * DM + hc + cxk], &Ks[nbf][(w * 32 + i * 8) * 64]);
                const int vr = w * 16 + i * 4 + l4;
                const int cxv = ((lane & 15) ^ ((i * 4 + l4) & 7)) * 8;
                gld16(&Vt[(size_t)(hc + vr) * SEQ + nkt * 128 + cxv], &Vs[nbf][(w * 16 + i * 4) * 128]);
            }
        }

        const u16* ksb = Ks[cur];
        const u16* vsb = Vs[cur];

#pragma unroll
        for (int h = 0; h < 2; ++h) {          // two 64-k sub-tiles per stage
            const int t64 = kt * 2 + h;
            if (t64 > dw) continue;            // fully masked (wave-uniform)

#pragma unroll
            for (int p = 0; p < 2; ++p) {      // st-pair within sub-tile
                const int ph = 2 * h + p;      // 32-s group index 0..3
                uint4 pa_raw[4];

#pragma unroll
                for (int stt = 0; stt < 2; ++stt) {
                    const int st = ph * 2 + stt;   // 0..7 (16-s row group)
                    bf16x8 kf[2];
#pragma unroll
                    for (int c = 0; c < 2; ++c)
                        kf[c] = *(const bf16x8*)&ksb[(st * 16 + m) * 64 + (((c * 4 + quad) ^ m7) * 8)];

                    f32x4 sc[4];
#pragma unroll
                    for (int qt4 = 0; qt4 < 4; ++qt4) {
                        f32x4 a = {};
                        a = mfma16(kf[0], qf[qt4][0], a);
                        a = mfma16(kf[1], qf[qt4][1], a);
                        sc[qt4] = a;
                    }

                    if (t64 == dw) {
                        const int stl = 2 * p + stt;   // st within sub-tile
#pragma unroll
                        for (int qt4 = 0; qt4 < 4; ++qt4)
#pragma unroll
                            for (int r = 0; r < 4; ++r) {
                                float pp = __builtin_amdgcn_exp2f(sc[qt4][r]);
                                sc[qt4][r] = (stl * 16 + quad * 4 + r > qt4 * 16 + m) ? 0.f : pp;
                            }
                    } else {
#pragma unroll
                        for (int qt4 = 0; qt4 < 4; ++qt4)
#pragma unroll
                            for (int r = 0; r < 4; ++r)
                                sc[qt4][r] = __builtin_amdgcn_exp2f(sc[qt4][r]);
                    }

#pragma unroll
                    for (int qt4 = 0; qt4 < 4; ++qt4) {
                        l_part[qt4] += sc[qt4][0] + sc[qt4][1] + sc[qt4][2] + sc[qt4][3];
                        const u32 pk0 = bfpack(sc[qt4][0], sc[qt4][1]);
                        const u32 pk1 = bfpack(sc[qt4][2], sc[qt4][3]);
                        if (stt == 0) { pa_raw[qt4].x = pk0; pa_raw[qt4].y = pk1; }
                        else          { pa_raw[qt4].z = pk0; pa_raw[qt4].w = pk1; }
                    }
                }

                bf16x8 pa[4];
#pragma unroll
                for (int qt4 = 0; qt4 < 4; ++qt4) __builtin_memcpy(&pa[qt4], &pa_raw[qt4], 16);

                // O += P.V over s in [32*ph, 32*ph+32): full K=32 MFMAs
#pragma unroll
                for (int dt = 0; dt < 4; ++dt) {
                    const int base = (dt * 16 + m) * 128;
                    const int clo = ((4 * ph + (quad >> 1)) ^ m7) * 8 + (quad & 1) * 4;
                    const int chi = ((4 * ph + 2 + (quad >> 1)) ^ m7) * 8 + (quad & 1) * 4;
                    uint2 vlo = *(const uint2*)&vsb[base + clo];
                    uint2 vhi = *(const uint2*)&vsb[base + chi];
                    uint4 t;
                    t.x = vlo.x; t.y = vlo.y; t.z = vhi.x; t.w = vhi.y;
                    bf16x8 vf;
                    __builtin_memcpy(&vf, &t, 16);
#pragma unroll
                    for (int qt4 = 0; qt4 < 4; ++qt4)
                        o_acc[qt4][dt] = mfma16(pa[qt4], vf, o_acc[qt4][dt]);
                }
            }
        }
    }

    // ---- reduce l across the 4 quads (same q=m per quad-group) ----
#pragma unroll
    for (int qt4 = 0; qt4 < 4; ++qt4) {
        l_part[qt4] += __shfl_xor(l_part[qt4], 16, 64);
        l_part[qt4] += __shfl_xor(l_part[qt4], 32, 64);
    }

    // ---- store unnormalized numerator + l to this part's slot ----
    u16*   dst = (part == 0) ? slot0 : ((part == 1) ? slot1 : slot2);
    float* lb  = (part == 0) ? l0 : ((part == 1) ? l1 : l2);
#pragma unroll
    for (int qt4 = 0; qt4 < 4; ++qt4)
#pragma unroll
        for (int dt = 0; dt < 4; ++dt)
#pragma unroll
            for (int r = 0; r < 4; ++r) {
                int row = qw + qt4 * 16 + quad * 4 + r;
                dst[(size_t)row * DM + hc + dt * 16 + m] = f2bf(o_acc[qt4][dt][r]);
            }
    if (lane < 16) {
#pragma unroll
        for (int qt4 = 0; qt4 < 4; ++qt4)
            lb[head * SEQ + qw + qt4 * 16 + lane] = l_part[qt4];
    }
}

// Merge thirds in place: s0 = (s0+s1+s2) / (l0+l1+l2), all rows.
__global__ __launch_bounds__(256) void merge_k(u16* __restrict__ s0,
                                               const u16* __restrict__ s1,
                                               const u16* __restrict__ s2,
                                               const float* __restrict__ l0,
                                               const float* __restrict__ l1,
                                               const float* __restrict__ l2) {
    const int gid = blockIdx.x * 256 + threadIdx.x;  // SEQ*128 threads
    const int rl = gid >> 7;
    const int cg = gid & 127;
    const int h  = cg >> 3;
    const float inv = 1.0f / (l0[h * SEQ + rl] + l1[h * SEQ + rl] + l2[h * SEQ + rl]);
    uint4 va = *(const uint4*)(s0 + (size_t)rl * DM + cg * 8);
    uint4 vb = *(const uint4*)(s1 + (size_t)rl * DM + cg * 8);
    uint4 vc = *(const uint4*)(s2 + (size_t)rl * DM + cg * 8);
    const u16* a16 = (const u16*)&va;
    const u16* b16 = (const u16*)&vb;
    const u16* c16 = (const u16*)&vc;
    u16 oo[8];
#pragma unroll
    for (int i = 0; i < 8; ++i)
        oo[i] = f2bf((bf2f(a16[i]) + bf2f(b16[i]) + bf2f(c16[i])) * inv);
    *(uint4*)(s0 + (size_t)rl * DM + cg * 8) = *(const uint4*)&oo[0];
}

// ---------------------------------------------------------------------------
extern "C" void kernel_launch(void* const* d_in, const int* in_sizes, int n_in,
                              void* d_out, int out_size, void* d_ws, size_t ws_size,
                              hipStream_t stream) {
    (void)in_sizes; (void)n_in; (void)out_size; (void)ws_size;

    u16* ws    = (u16*)d_ws;
    int* flags = (int*)d_ws;                       // [0]=dtype, [1]=0
    u16* xc    = ws + 64;                          // SEQ*DM; Vt_g overlays after QKV GEMM
    u16* Vt_g  = xc;
    u16* Wtqkv = xc + (size_t)SEQ * DM;            // 3*DM*DM (q scaled QSCALE); -> l0/l1/l2
    u16* Wto   = Wtqkv + (size_t)3 * DM * DM;      // DM*DM
    u16* bqkv  = Wto + (size_t)DM * DM;            // 3*DM
    u16* boc   = bqkv + 3 * DM;                    // DM
    u16* Qb    = boc + DM;                         // SEQ*DM
    u16* Kb    = Qb + (size_t)SEQ * DM;            // SEQ*DM
    u16* Vb    = Kb + (size_t)SEQ * DM;            // SEQ*DM; dead after vt_k -> slot2
    u16* ab    = Vb + (size_t)SEQ * DM;            // SEQ*DM (slot0 -> merged O)
    u16* slotB = ab + (size_t)SEQ * DM;            // SEQ*DM (slot1)
    u16* slotC = Vb;                               // overlays dead V buffer
    float* l0f = (float*)Wtqkv;                    // NH*SEQ each (overlay dead Wtqkv)
    float* l1f = l0f + NH * SEQ;
    float* l2f = l1f + NH * SEQ;
    // total ~56 MB, same footprint as rounds 5-9.

    detect_k<<<1, 256, 0, stream>>>((const u16*)d_in[1], flags);

    prep_w<<<dim3(DM / 32, DM / 32, 4), 256, 0, stream>>>(
        d_in[1], d_in[3], d_in[5], d_in[7],
        d_in[2], d_in[4], d_in[6], d_in[8],
        Wtqkv, bqkv, flags);

    cvt_x8<<<SEQ * DM / 2048, 256, 0, stream>>>(d_in[0], xc, flags);

    // Fused QKV projection -> separate Q, K, V buffers (bf16)
    gemm128<<<dim3(SEQ / 128, 3 * DM / 128), 256, 0, stream>>>(
        xc, Wtqkv, bqkv, Qb, Kb, Vb, SEQ, 3 * DM, DM, flags + 1);

    // Per-head V^T (xc dead; Vt_g overlays it)
    vt_k<<<dim3(SEQ / 64, NH), 256, 0, stream>>>(Vb, Vt_g);

    attn_split<<<dim3(768), 256, 0, stream>>>(Qb, Kb, Vt_g, ab, slotB, slotC,
                                              l0f, l1f, l2f);

    merge_k<<<dim3(SEQ * 128 / 256), 256, 0, stream>>>(ab, slotB, slotC, l0f, l1f, l2f);

    // Out projection: 128x64 tiles -> 512 blocks (2/CU)
    gemm_n64<<<dim3(SEQ / 128, DM / 64), 256, 0, stream>>>(
        ab, Wto, boc, d_out, SEQ, DM, DM, flags);
}